// Round 6
// baseline (350.823 us; speedup 1.0000x reference)
//
#include <hip/hip_runtime.h>

// LSS view transform, chunked-gather formulation, sharded + wave-run binning.
// out[b,c,cell] = sum_{(pix,d)->cell} img[b,c,pix] * dp[b,d,pix]
// Round-6 changes:
//  - gather: thread = 4 channels (float4 loads, 16B/lane), 4 entry subsequences
//    per block with private accumulators; CHUNK 64->128.
//  - count/fill: wave-run aggregation (consecutive lanes = consecutive pixels;
//    leader lane does ONE atomic per equal-cell run, lanes write base+rank).
constexpr int IMG_H = 48, IMG_W = 160;
constexpr int HW    = IMG_H * IMG_W;          // 7680
constexpr int BEV_H = 128, BEV_W = 128;
constexpr int NCELL = BEV_H * BEV_W;          // 16384 per batch
constexpr int C_DIM = 128, D_DIM = 64, B_DIM = 2;
constexpr int NCELL_TOT = B_DIM * NCELL;      // 32768
constexpr int NPIX_TOT  = B_DIM * HW;         // 15360
constexpr int NPTS      = NPIX_TOT * D_DIM;   // 983040
constexpr int MAX_ENTRIES = NPTS;
constexpr int CHUNK = 128;
constexpr int NSHARD = 16;
constexpr float X_MIN = -51.2f, Y_MIN = -51.2f;
constexpr float RES_X = 102.4f / 128.0f;
constexpr float RES_Y = 102.4f / 128.0f;

// ---- ws layout (4-byte words), 16.12 MB total (proven footprint) ----
constexpr size_t WS_IMG_T = 0;                                      // float[B*HW*C] 1966080
constexpr size_t WS_HIST2 = WS_IMG_T + (size_t)B_DIM * HW * C_DIM;  // int[NSHARD*32768] shard-major
constexpr size_t WS_HIST  = WS_HIST2 + (size_t)NSHARD * NCELL_TOT;  // int[32768]
constexpr size_t WS_OFFS  = WS_HIST + NCELL_TOT;                    // int[32769] (+3 pad)
constexpr size_t WS_EKEY  = WS_OFFS + NCELL_TOT + 4;                // int[MAX_ENTRIES]
constexpr size_t WS_EW16  = WS_EKEY + MAX_ENTRIES;                  // ushort[MAX_ENTRIES]

__device__ inline int point_shard(int tid) {
    return ((tid >> 2) + (tid >> 8)) & (NSHARD - 1);   // deterministic in tid
}

__device__ inline void make_ray(const float* __restrict__ K, int b, float gx, float gy,
                                float& rx, float& ry, float& rz) {
    const float* Kb = K + b * 9;
    const float a00 = Kb[0], a01 = Kb[1], a02 = Kb[2];
    const float a10 = Kb[3], a11 = Kb[4], a12 = Kb[5];
    const float a20 = Kb[6], a21 = Kb[7], a22 = Kb[8];
    const float det = a00 * (a11 * a22 - a12 * a21)
                    - a01 * (a10 * a22 - a12 * a20)
                    + a02 * (a10 * a21 - a11 * a20);
    const float inv = 1.0f / det;
    const float i00 =  (a11 * a22 - a12 * a21) * inv;
    const float i01 = -(a01 * a22 - a02 * a21) * inv;
    const float i02 =  (a01 * a12 - a02 * a11) * inv;
    const float i10 = -(a10 * a22 - a12 * a20) * inv;
    const float i11 =  (a00 * a22 - a02 * a20) * inv;
    const float i12 = -(a00 * a12 - a02 * a10) * inv;
    const float i20 =  (a10 * a21 - a11 * a20) * inv;
    const float i21 = -(a00 * a21 - a01 * a20) * inv;
    const float i22 =  (a00 * a11 - a01 * a10) * inv;
    rx = i00 * gx + i01 * gy + i02;
    ry = i10 * gx + i11 * gy + i12;
    rz = i20 * gx + i21 * gy + i22;
}

// Returns global cell id (b*NCELL + cell) or -1. tid = ((b*D + d)*HW + pix).
__device__ inline int point_gcell(int tid, const float* __restrict__ dv,
                                  const float* __restrict__ K,
                                  const float* __restrict__ T) {
    const int pix = tid % HW;
    const int bd  = tid / HW;
    const int d   = bd % D_DIM;
    const int b   = bd / D_DIM;
    const int h = pix / IMG_W, w = pix % IMG_W;
    float rx, ry, rz;
    make_ray(K, b, (float)w, (float)h, rx, ry, rz);
    const float* Tb = T + b * 16;
    const float dep = dv[d];                       // wave-uniform
    const float px = dep * rx, py = dep * ry, pz = dep * rz;
    const float x = Tb[0] * px + Tb[1] * py + Tb[2]  * pz + Tb[3];
    const float y = Tb[4] * px + Tb[5] * py + Tb[6]  * pz + Tb[7];
    const float z = Tb[8] * px + Tb[9] * py + Tb[10] * pz + Tb[11];
    const int bx = (int)((x - X_MIN) / RES_X);     // truncate-toward-zero == astype(int32)
    const int by = (int)((y - Y_MIN) / RES_Y);
    const bool valid = (bx >= 0) && (bx < BEV_W) && (by >= 0) && (by < BEV_H) && (z > 0.0f);
    return valid ? (b * NCELL + by * BEV_W + bx) : -1;
}

// Wave-run helpers: lanes are consecutive pixels -> equal-cell runs.
// Returns is_leader; fills run_len (valid for leaders) and leader_idx (all lanes).
__device__ inline bool wave_runs(int gcell, int lane, int& run_len, int& leader_idx) {
    const int left = __shfl_up(gcell, 1);          // width 64
    const bool is_leader = (lane == 0) || (left != gcell);
    const unsigned long long lmask = __ballot(is_leader);
    // next leader strictly after me
    const unsigned long long rest = (lane == 63) ? 0ULL : (lmask >> (lane + 1));
    const int f = __ffsll((unsigned long long)rest);   // 1+idx or 0
    run_len = f ? f : (64 - lane);
    // my leader = highest set bit <= lane
    const unsigned long long below =
        lmask & ((lane == 63) ? ~0ULL : ((1ULL << (lane + 1)) - 1ULL));
    leader_idx = 63 - __clzll((long long)below);
    return is_leader;
}

// ---- K1: tiled transpose img[b,c,pix] -> img_t[b,pix,c] ----
__global__ __launch_bounds__(256) void k_transpose(const float* __restrict__ img,
                                                   float* __restrict__ img_t) {
    __shared__ float tile[32][33];
    const int b = blockIdx.z;
    const int tx = threadIdx.x, ty = threadIdx.y;      // block (32, 8)
    const int pix0 = blockIdx.x * 32, c0 = blockIdx.y * 32;
    #pragma unroll
    for (int j = 0; j < 32; j += 8)
        tile[ty + j][tx] = img[((size_t)(b * C_DIM + c0 + ty + j)) * HW + pix0 + tx];
    __syncthreads();
    #pragma unroll
    for (int j = 0; j < 32; j += 8)
        img_t[((size_t)(b * HW + pix0 + ty + j)) * C_DIM + c0 + tx] = tile[tx][ty + j];
}

// ---- K2: sharded count, one atomic per equal-cell run ----
__global__ __launch_bounds__(256) void k_count(const float* __restrict__ dv,
                                               const float* __restrict__ K,
                                               const float* __restrict__ T,
                                               int* __restrict__ hist2) {
    const int tid = blockIdx.x * 256 + threadIdx.x;   // < NPTS (exact grid)
    const int gcell = point_gcell(tid, dv, K, T);
    const int lane = threadIdx.x & 63;
    int run_len, leader_idx;
    const bool lead = wave_runs(gcell, lane, run_len, leader_idx);
    if (lead && gcell >= 0)
        atomicAdd(&hist2[(size_t)point_shard(tid) * NCELL_TOT + gcell], run_len);
}

// ---- K2b: reduce shards -> per-cell totals ----
__global__ __launch_bounds__(256) void k_reduce(const int* __restrict__ hist2,
                                                int* __restrict__ hist) {
    const int cell = blockIdx.x * 256 + threadIdx.x;  // 128 blocks exact
    int s = 0;
    #pragma unroll
    for (int sh = 0; sh < NSHARD; ++sh)
        s += hist2[(size_t)sh * NCELL_TOT + cell];
    hist[cell] = s;
}

// ---- K3: exclusive prefix scan over hist[32768] -> offs[32769] ----
__global__ __launch_bounds__(1024) void k_scan(const int* __restrict__ hist,
                                               int* __restrict__ offs) {
    __shared__ int lds[1024];
    const int t = threadIdx.x;
    int h[32];
    int s = 0;
    const int base = t * 32;
    #pragma unroll
    for (int k = 0; k < 32; ++k) { h[k] = hist[base + k]; s += h[k]; }
    lds[t] = s;
    __syncthreads();
    for (int off = 1; off < 1024; off <<= 1) {
        int v = (t >= off) ? lds[t - off] : 0;
        __syncthreads();
        lds[t] += v;
        __syncthreads();
    }
    int run = lds[t] - s;   // exclusive base for this thread's chunk
    #pragma unroll
    for (int k = 0; k < 32; ++k) {
        offs[base + k] = run;
        run += h[k];
    }
    if (t == 1023) offs[NCELL_TOT] = lds[1023];
}

// ---- K3b: per-cell shard prefix; hist2 becomes cursor bases in place ----
__global__ __launch_bounds__(256) void k_shardbase(int* __restrict__ hist2,
                                                   const int* __restrict__ offs) {
    const int cell = blockIdx.x * 256 + threadIdx.x;  // 128 blocks exact
    int run = offs[cell];
    #pragma unroll
    for (int sh = 0; sh < NSHARD; ++sh) {
        const size_t idx = (size_t)sh * NCELL_TOT + cell;
        const int cnt = hist2[idx];
        hist2[idx] = run;
        run += cnt;
    }
}

// ---- K4: fill entries; leader reserves a span per run, lanes write base+rank ----
__global__ __launch_bounds__(256) void k_fill(const float* __restrict__ dp,
                                              const float* __restrict__ dv,
                                              const float* __restrict__ K,
                                              const float* __restrict__ T,
                                              int* __restrict__ cursor2,   // = hist2 (bases)
                                              int* __restrict__ ekey,
                                              unsigned short* __restrict__ ew16) {
    const int tid = blockIdx.x * 256 + threadIdx.x;   // < NPTS (exact grid)
    const int gcell = point_gcell(tid, dv, K, T);
    const int lane = threadIdx.x & 63;
    int run_len, leader_idx;
    const bool lead = wave_runs(gcell, lane, run_len, leader_idx);
    int base = 0;
    if (lead && gcell >= 0)
        base = atomicAdd(&cursor2[(size_t)point_shard(tid) * NCELL_TOT + gcell], run_len);
    base = __shfl(base, leader_idx);                  // broadcast my run's base
    if (gcell < 0) return;
    const int slot = base + (lane - leader_idx);      // contiguous, coalesced writes
    const float p = dp[tid];                          // tid == ((b*D+d)*HW+pix): coalesced
    ekey[slot] = (gcell << 13) | (tid % HW);
    ew16[slot] = (unsigned short)__float2uint_rn(p * 65535.0f);
}

// ---- K5: chunked segmented reduction. Block = 128 entries; thread = 4 channels
// (float4). Quarter q processes entries k*4+q with a private accumulator; all
// flushes are atomic -> partial sums per quarter are safe. ----
__global__ __launch_bounds__(128) void k_chunk_gather(
    const float* __restrict__ img_t,
    const int* __restrict__ offs,     // offs[NCELL_TOT] = total entry count
    const int* __restrict__ ekey,
    const unsigned short* __restrict__ ew16,
    float* __restrict__ out)
{
    const int total = offs[NCELL_TOT];
    const int base = blockIdx.x * CHUNK;
    if (base >= total) return;

    __shared__ int   s_key[CHUNK];
    __shared__ float s_w[CHUNK];
    {
        const int i = threadIdx.x;                               // 128 threads
        const int idx = min(base + i, total - 1);
        s_key[i] = ekey[idx];                                    // pad = dup of last key
        s_w[i]   = (base + i < total) ? (float)ew16[base + i] * (1.0f / 65535.0f)
                                      : 0.0f;                    // pad weight 0 -> no-op
    }
    __syncthreads();

    const int q  = threadIdx.x >> 5;      // quarter 0..3
    const int l  = threadIdx.x & 31;      // lane in quarter
    const int c4 = l * 4;                 // channels c4..c4+3

    float4 acc = make_float4(0.f, 0.f, 0.f, 0.f);
    int prev = s_key[q] >> 13;

    #pragma unroll 8
    for (int kk = 0; kk < CHUNK / 4; ++kk) {         // 32 entries per quarter
        const int key = s_key[kk * 4 + q];           // LDS broadcast (quarter-uniform)
        const float wgt = s_w[kk * 4 + q];
        const int gcell = key >> 13;
        const int pix = key & 8191;
        const int b = gcell >> 14;
        const float4 v = *reinterpret_cast<const float4*>(
            &img_t[((size_t)(b * HW + pix)) * C_DIM + c4]);      // 16B/lane, coalesced
        if (gcell != prev) {                         // quarter-uniform branch
            const int pb = prev >> 14, pc = prev & (NCELL - 1);
            float* o = &out[((size_t)(pb * C_DIM + c4)) * NCELL + pc];
            atomicAdd(o, acc.x);
            atomicAdd(o + NCELL, acc.y);
            atomicAdd(o + 2 * NCELL, acc.z);
            atomicAdd(o + 3 * NCELL, acc.w);
            acc = make_float4(0.f, 0.f, 0.f, 0.f);
            prev = gcell;
        }
        acc.x = fmaf(v.x, wgt, acc.x);
        acc.y = fmaf(v.y, wgt, acc.y);
        acc.z = fmaf(v.z, wgt, acc.z);
        acc.w = fmaf(v.w, wgt, acc.w);
    }
    const int pb = prev >> 14, pc = prev & (NCELL - 1);
    float* o = &out[((size_t)(pb * C_DIM + c4)) * NCELL + pc];
    atomicAdd(o, acc.x);
    atomicAdd(o + NCELL, acc.y);
    atomicAdd(o + 2 * NCELL, acc.z);
    atomicAdd(o + 3 * NCELL, acc.w);
}

extern "C" void kernel_launch(void* const* d_in, const int* in_sizes, int n_in,
                              void* d_out, int out_size, void* d_ws, size_t ws_size,
                              hipStream_t stream) {
    const float* img = (const float*)d_in[0];
    const float* dp  = (const float*)d_in[1];
    const float* dv  = (const float*)d_in[2];
    const float* K   = (const float*)d_in[3];
    const float* T   = (const float*)d_in[4];
    float* out = (float*)d_out;

    float* ws_f   = (float*)d_ws;
    float* img_t  = ws_f + WS_IMG_T;
    int*   hist2  = (int*)d_ws + WS_HIST2;
    int*   hist   = (int*)d_ws + WS_HIST;
    int*   offs   = (int*)d_ws + WS_OFFS;
    int*   ekey   = (int*)d_ws + WS_EKEY;
    unsigned short* ew16 = (unsigned short*)((int*)d_ws + WS_EW16);

    hipMemsetAsync(hist2, 0, (size_t)NSHARD * NCELL_TOT * sizeof(int), stream);
    hipMemsetAsync(out, 0, (size_t)out_size * sizeof(float), stream);

    k_transpose<<<dim3(HW / 32, C_DIM / 32, B_DIM), dim3(32, 8), 0, stream>>>(img, img_t);
    k_count<<<NPTS / 256, 256, 0, stream>>>(dv, K, T, hist2);
    k_reduce<<<NCELL_TOT / 256, 256, 0, stream>>>(hist2, hist);
    k_scan<<<1, 1024, 0, stream>>>(hist, offs);
    k_shardbase<<<NCELL_TOT / 256, 256, 0, stream>>>(hist2, offs);
    k_fill<<<NPTS / 256, 256, 0, stream>>>(dp, dv, K, T, hist2, ekey, ew16);
    k_chunk_gather<<<MAX_ENTRIES / CHUNK, 128, 0, stream>>>(img_t, offs, ekey, ew16, out);
}

// Round 7
// 181.039 us; speedup vs baseline: 1.9378x; 1.9378x over previous
//
#include <hip/hip_runtime.h>

// LSS view transform, chunked-gather formulation, sharded + wave-run binning.
// out[b,c,cell] = sum_{(pix,d)->cell} img[b,c,pix] * dp[b,d,pix]
// Round-7 change: gather reverts to the proven round-5 structure (CHUNK=64,
// thread=channel, scalar row loads) but flushes atomics into a CELL-MAJOR
// accumulator out_t[b][cell][c] (128 consecutive floats per flush = 8 cache
// lines, vs 128 scattered 64KB-strided lines). Final tiled untranspose writes
// d_out. Host-side fallback to direct-to-out flush if ws_size is too small.
constexpr int IMG_H = 48, IMG_W = 160;
constexpr int HW    = IMG_H * IMG_W;          // 7680
constexpr int BEV_H = 128, BEV_W = 128;
constexpr int NCELL = BEV_H * BEV_W;          // 16384 per batch
constexpr int C_DIM = 128, D_DIM = 64, B_DIM = 2;
constexpr int NCELL_TOT = B_DIM * NCELL;      // 32768
constexpr int NPIX_TOT  = B_DIM * HW;         // 15360
constexpr int NPTS      = NPIX_TOT * D_DIM;   // 983040
constexpr int MAX_ENTRIES = NPTS;
constexpr int CHUNK = 64;
constexpr int NSHARD = 16;
constexpr float X_MIN = -51.2f, Y_MIN = -51.2f;
constexpr float RES_X = 102.4f / 128.0f;
constexpr float RES_Y = 102.4f / 128.0f;

// ---- ws layout (4-byte words) ----
constexpr size_t WS_IMG_T = 0;                                      // float[B*HW*C] 1966080
constexpr size_t WS_HIST2 = WS_IMG_T + (size_t)B_DIM * HW * C_DIM;  // int[NSHARD*32768]
constexpr size_t WS_HIST  = WS_HIST2 + (size_t)NSHARD * NCELL_TOT;  // int[32768]
constexpr size_t WS_OFFS  = WS_HIST + NCELL_TOT;                    // int[32769] (+3 pad)
constexpr size_t WS_EKEY  = WS_OFFS + NCELL_TOT + 4;                // int[MAX_ENTRIES]
constexpr size_t WS_EW16  = WS_EKEY + MAX_ENTRIES;                  // ushort[MAX_ENTRIES]
constexpr size_t WS_OUT_T = WS_EW16 + MAX_ENTRIES / 2;              // float[NCELL_TOT*C] 4194304
constexpr size_t WS_NEED_CM = (WS_OUT_T + (size_t)NCELL_TOT * C_DIM) * 4;  // bytes, ~31.4 MB
constexpr size_t WS_NEED_FB = WS_OUT_T * 4;                                // fallback, ~16.1 MB

__device__ inline int point_shard(int tid) {
    return ((tid >> 2) + (tid >> 8)) & (NSHARD - 1);   // deterministic in tid
}

__device__ inline void make_ray(const float* __restrict__ K, int b, float gx, float gy,
                                float& rx, float& ry, float& rz) {
    const float* Kb = K + b * 9;
    const float a00 = Kb[0], a01 = Kb[1], a02 = Kb[2];
    const float a10 = Kb[3], a11 = Kb[4], a12 = Kb[5];
    const float a20 = Kb[6], a21 = Kb[7], a22 = Kb[8];
    const float det = a00 * (a11 * a22 - a12 * a21)
                    - a01 * (a10 * a22 - a12 * a20)
                    + a02 * (a10 * a21 - a11 * a20);
    const float inv = 1.0f / det;
    const float i00 =  (a11 * a22 - a12 * a21) * inv;
    const float i01 = -(a01 * a22 - a02 * a21) * inv;
    const float i02 =  (a01 * a12 - a02 * a11) * inv;
    const float i10 = -(a10 * a22 - a12 * a20) * inv;
    const float i11 =  (a00 * a22 - a02 * a20) * inv;
    const float i12 = -(a00 * a12 - a02 * a10) * inv;
    const float i20 =  (a10 * a21 - a11 * a20) * inv;
    const float i21 = -(a00 * a21 - a01 * a20) * inv;
    const float i22 =  (a00 * a11 - a01 * a10) * inv;
    rx = i00 * gx + i01 * gy + i02;
    ry = i10 * gx + i11 * gy + i12;
    rz = i20 * gx + i21 * gy + i22;
}

// Returns global cell id (b*NCELL + cell) or -1. tid = ((b*D + d)*HW + pix).
__device__ inline int point_gcell(int tid, const float* __restrict__ dv,
                                  const float* __restrict__ K,
                                  const float* __restrict__ T) {
    const int pix = tid % HW;
    const int bd  = tid / HW;
    const int d   = bd % D_DIM;
    const int b   = bd / D_DIM;
    const int h = pix / IMG_W, w = pix % IMG_W;
    float rx, ry, rz;
    make_ray(K, b, (float)w, (float)h, rx, ry, rz);
    const float* Tb = T + b * 16;
    const float dep = dv[d];                       // wave-uniform
    const float px = dep * rx, py = dep * ry, pz = dep * rz;
    const float x = Tb[0] * px + Tb[1] * py + Tb[2]  * pz + Tb[3];
    const float y = Tb[4] * px + Tb[5] * py + Tb[6]  * pz + Tb[7];
    const float z = Tb[8] * px + Tb[9] * py + Tb[10] * pz + Tb[11];
    const int bx = (int)((x - X_MIN) / RES_X);     // truncate-toward-zero == astype(int32)
    const int by = (int)((y - Y_MIN) / RES_Y);
    const bool valid = (bx >= 0) && (bx < BEV_W) && (by >= 0) && (by < BEV_H) && (z > 0.0f);
    return valid ? (b * NCELL + by * BEV_W + bx) : -1;
}

// Wave-run helpers: lanes are consecutive pixels -> equal-cell runs.
__device__ inline bool wave_runs(int gcell, int lane, int& run_len, int& leader_idx) {
    const int left = __shfl_up(gcell, 1);          // width 64
    const bool is_leader = (lane == 0) || (left != gcell);
    const unsigned long long lmask = __ballot(is_leader);
    const unsigned long long rest = (lane == 63) ? 0ULL : (lmask >> (lane + 1));
    const int f = __ffsll((unsigned long long)rest);   // 1+idx or 0
    run_len = f ? f : (64 - lane);
    const unsigned long long below =
        lmask & ((lane == 63) ? ~0ULL : ((1ULL << (lane + 1)) - 1ULL));
    leader_idx = 63 - __clzll((long long)below);
    return is_leader;
}

// ---- K1: tiled transpose img[b,c,pix] -> img_t[b,pix,c] ----
__global__ __launch_bounds__(256) void k_transpose(const float* __restrict__ img,
                                                   float* __restrict__ img_t) {
    __shared__ float tile[32][33];
    const int b = blockIdx.z;
    const int tx = threadIdx.x, ty = threadIdx.y;      // block (32, 8)
    const int pix0 = blockIdx.x * 32, c0 = blockIdx.y * 32;
    #pragma unroll
    for (int j = 0; j < 32; j += 8)
        tile[ty + j][tx] = img[((size_t)(b * C_DIM + c0 + ty + j)) * HW + pix0 + tx];
    __syncthreads();
    #pragma unroll
    for (int j = 0; j < 32; j += 8)
        img_t[((size_t)(b * HW + pix0 + ty + j)) * C_DIM + c0 + tx] = tile[tx][ty + j];
}

// ---- K2: sharded count, one atomic per equal-cell run ----
__global__ __launch_bounds__(256) void k_count(const float* __restrict__ dv,
                                               const float* __restrict__ K,
                                               const float* __restrict__ T,
                                               int* __restrict__ hist2) {
    const int tid = blockIdx.x * 256 + threadIdx.x;   // < NPTS (exact grid)
    const int gcell = point_gcell(tid, dv, K, T);
    const int lane = threadIdx.x & 63;
    int run_len, leader_idx;
    const bool lead = wave_runs(gcell, lane, run_len, leader_idx);
    if (lead && gcell >= 0)
        atomicAdd(&hist2[(size_t)point_shard(tid) * NCELL_TOT + gcell], run_len);
}

// ---- K2b: reduce shards -> per-cell totals ----
__global__ __launch_bounds__(256) void k_reduce(const int* __restrict__ hist2,
                                                int* __restrict__ hist) {
    const int cell = blockIdx.x * 256 + threadIdx.x;  // 128 blocks exact
    int s = 0;
    #pragma unroll
    for (int sh = 0; sh < NSHARD; ++sh)
        s += hist2[(size_t)sh * NCELL_TOT + cell];
    hist[cell] = s;
}

// ---- K3: exclusive prefix scan over hist[32768] -> offs[32769] ----
__global__ __launch_bounds__(1024) void k_scan(const int* __restrict__ hist,
                                               int* __restrict__ offs) {
    __shared__ int lds[1024];
    const int t = threadIdx.x;
    int h[32];
    int s = 0;
    const int base = t * 32;
    #pragma unroll
    for (int k = 0; k < 32; ++k) { h[k] = hist[base + k]; s += h[k]; }
    lds[t] = s;
    __syncthreads();
    for (int off = 1; off < 1024; off <<= 1) {
        int v = (t >= off) ? lds[t - off] : 0;
        __syncthreads();
        lds[t] += v;
        __syncthreads();
    }
    int run = lds[t] - s;   // exclusive base for this thread's chunk
    #pragma unroll
    for (int k = 0; k < 32; ++k) {
        offs[base + k] = run;
        run += h[k];
    }
    if (t == 1023) offs[NCELL_TOT] = lds[1023];
}

// ---- K3b: per-cell shard prefix; hist2 becomes cursor bases in place ----
__global__ __launch_bounds__(256) void k_shardbase(int* __restrict__ hist2,
                                                   const int* __restrict__ offs) {
    const int cell = blockIdx.x * 256 + threadIdx.x;  // 128 blocks exact
    int run = offs[cell];
    #pragma unroll
    for (int sh = 0; sh < NSHARD; ++sh) {
        const size_t idx = (size_t)sh * NCELL_TOT + cell;
        const int cnt = hist2[idx];
        hist2[idx] = run;
        run += cnt;
    }
}

// ---- K4: fill entries; leader reserves a span per run, lanes write base+rank ----
__global__ __launch_bounds__(256) void k_fill(const float* __restrict__ dp,
                                              const float* __restrict__ dv,
                                              const float* __restrict__ K,
                                              const float* __restrict__ T,
                                              int* __restrict__ cursor2,   // = hist2 (bases)
                                              int* __restrict__ ekey,
                                              unsigned short* __restrict__ ew16) {
    const int tid = blockIdx.x * 256 + threadIdx.x;   // < NPTS (exact grid)
    const int gcell = point_gcell(tid, dv, K, T);
    const int lane = threadIdx.x & 63;
    int run_len, leader_idx;
    const bool lead = wave_runs(gcell, lane, run_len, leader_idx);
    int base = 0;
    if (lead && gcell >= 0)
        base = atomicAdd(&cursor2[(size_t)point_shard(tid) * NCELL_TOT + gcell], run_len);
    base = __shfl(base, leader_idx);                  // broadcast my run's base
    if (gcell < 0) return;
    const int slot = base + (lane - leader_idx);      // contiguous, coalesced writes
    const float p = dp[tid];                          // tid == ((b*D+d)*HW+pix): coalesced
    ekey[slot] = (gcell << 13) | (tid % HW);
    ew16[slot] = (unsigned short)__float2uint_rn(p * 65535.0f);
}

// ---- K5: chunked segmented reduction (round-5 structure).
// CELL_MAJOR: flush -> acc[gcell*C + c] (contiguous lines). else -> out layout.
template <bool CELL_MAJOR>
__global__ __launch_bounds__(128) void k_chunk_gather(
    const float* __restrict__ img_t,
    const int* __restrict__ offs,     // offs[NCELL_TOT] = total entry count
    const int* __restrict__ ekey,
    const unsigned short* __restrict__ ew16,
    float* __restrict__ acc_out)
{
    const int total = offs[NCELL_TOT];
    const int base = blockIdx.x * CHUNK;
    if (base >= total) return;

    __shared__ int   s_key[CHUNK];
    __shared__ float s_w[CHUNK];
    if (threadIdx.x < CHUNK) {
        const int i = threadIdx.x;
        const int idx = min(base + i, total - 1);
        s_key[i] = ekey[idx];                                   // pad = dup of last key
        s_w[i]   = (base + i < total) ? (float)ew16[base + i] * (1.0f / 65535.0f)
                                      : 0.0f;                   // pad weight 0 -> no-op
    }
    __syncthreads();

    const int c = threadIdx.x;
    int prev_gcell = s_key[0] >> 13;
    float acc = 0.0f;
    #pragma unroll 8
    for (int k = 0; k < CHUNK; ++k) {                // static trip count -> pipelined
        const int key = s_key[k];                    // LDS broadcast (wave-uniform)
        const int gcell = key >> 13;
        const int pix = key & 8191;
        const int b = gcell >> 14;
        const float v = img_t[((size_t)(b * HW + pix)) * C_DIM + c] * s_w[k];
        if (gcell != prev_gcell) {                   // wave-uniform branch
            if (CELL_MAJOR) {
                atomicAdd(&acc_out[(size_t)prev_gcell * C_DIM + c], acc);
            } else {
                const int pb = prev_gcell >> 14, pc = prev_gcell & (NCELL - 1);
                atomicAdd(&acc_out[((size_t)(pb * C_DIM + c)) * NCELL + pc], acc);
            }
            acc = 0.0f;
            prev_gcell = gcell;
        }
        acc += v;
    }
    if (CELL_MAJOR) {
        atomicAdd(&acc_out[(size_t)prev_gcell * C_DIM + c], acc);
    } else {
        const int pb = prev_gcell >> 14, pc = prev_gcell & (NCELL - 1);
        atomicAdd(&acc_out[((size_t)(pb * C_DIM + c)) * NCELL + pc], acc);
    }
}

// ---- K6: untranspose out_t[b][cell][c] -> out[b][c][cell] ----
__global__ __launch_bounds__(256) void k_untranspose(const float* __restrict__ out_t,
                                                     float* __restrict__ out) {
    __shared__ float tile[32][33];
    const int b = blockIdx.z;
    const int tx = threadIdx.x, ty = threadIdx.y;      // block (32, 8)
    const int cell0 = blockIdx.x * 32, c0 = blockIdx.y * 32;
    const float* src = out_t + (size_t)b * NCELL * C_DIM;
    #pragma unroll
    for (int j = 0; j < 32; j += 8)                    // read: c contiguous
        tile[ty + j][tx] = src[((size_t)(cell0 + ty + j)) * C_DIM + c0 + tx];
    __syncthreads();
    #pragma unroll
    for (int j = 0; j < 32; j += 8)                    // write: cell contiguous
        out[((size_t)(b * C_DIM + c0 + ty + j)) * NCELL + cell0 + tx] = tile[tx][ty + j];
}

extern "C" void kernel_launch(void* const* d_in, const int* in_sizes, int n_in,
                              void* d_out, int out_size, void* d_ws, size_t ws_size,
                              hipStream_t stream) {
    const float* img = (const float*)d_in[0];
    const float* dp  = (const float*)d_in[1];
    const float* dv  = (const float*)d_in[2];
    const float* K   = (const float*)d_in[3];
    const float* T   = (const float*)d_in[4];
    float* out = (float*)d_out;

    float* ws_f   = (float*)d_ws;
    float* img_t  = ws_f + WS_IMG_T;
    int*   hist2  = (int*)d_ws + WS_HIST2;
    int*   hist   = (int*)d_ws + WS_HIST;
    int*   offs   = (int*)d_ws + WS_OFFS;
    int*   ekey   = (int*)d_ws + WS_EKEY;
    unsigned short* ew16 = (unsigned short*)((int*)d_ws + WS_EW16);
    float* out_t  = ws_f + WS_OUT_T;

    const bool cell_major = (ws_size >= WS_NEED_CM);

    hipMemsetAsync(hist2, 0, (size_t)NSHARD * NCELL_TOT * sizeof(int), stream);
    if (cell_major)
        hipMemsetAsync(out_t, 0, (size_t)NCELL_TOT * C_DIM * sizeof(float), stream);
    else
        hipMemsetAsync(out, 0, (size_t)out_size * sizeof(float), stream);

    k_transpose<<<dim3(HW / 32, C_DIM / 32, B_DIM), dim3(32, 8), 0, stream>>>(img, img_t);
    k_count<<<NPTS / 256, 256, 0, stream>>>(dv, K, T, hist2);
    k_reduce<<<NCELL_TOT / 256, 256, 0, stream>>>(hist2, hist);
    k_scan<<<1, 1024, 0, stream>>>(hist, offs);
    k_shardbase<<<NCELL_TOT / 256, 256, 0, stream>>>(hist2, offs);
    k_fill<<<NPTS / 256, 256, 0, stream>>>(dp, dv, K, T, hist2, ekey, ew16);
    if (cell_major) {
        k_chunk_gather<true><<<MAX_ENTRIES / CHUNK, 128, 0, stream>>>(
            img_t, offs, ekey, ew16, out_t);
        k_untranspose<<<dim3(NCELL / 32, C_DIM / 32, B_DIM), dim3(32, 8), 0, stream>>>(
            out_t, out);
    } else {
        k_chunk_gather<false><<<MAX_ENTRIES / CHUNK, 128, 0, stream>>>(
            img_t, offs, ekey, ew16, out);
    }
}

// Round 8
// 164.738 us; speedup vs baseline: 2.1296x; 1.0989x over previous
//
#include <hip/hip_runtime.h>

// LSS view transform, chunked-gather formulation, sharded + wave-run binning,
// cell-major atomic accumulator.
// out[b,c,cell] = sum_{(pix,d)->cell} img[b,c,pix] * dp[b,d,pix]
// Round-8 changes:
//  - gather: one wave per block, thread = 2 channels (float2 loads: one VMEM
//    instr fetches the whole 512B row vs two in round 7). Flush = 2 consecutive
//    atomicAdds/lane -> same 128 atomic-floats per flush (round-6 lesson).
//  - ws reorder: out_t adjacent to hist2 -> single fused memset dispatch.
constexpr int IMG_H = 48, IMG_W = 160;
constexpr int HW    = IMG_H * IMG_W;          // 7680
constexpr int BEV_H = 128, BEV_W = 128;
constexpr int NCELL = BEV_H * BEV_W;          // 16384 per batch
constexpr int C_DIM = 128, D_DIM = 64, B_DIM = 2;
constexpr int NCELL_TOT = B_DIM * NCELL;      // 32768
constexpr int NPIX_TOT  = B_DIM * HW;         // 15360
constexpr int NPTS      = NPIX_TOT * D_DIM;   // 983040
constexpr int MAX_ENTRIES = NPTS;
constexpr int CHUNK = 64;
constexpr int NSHARD = 16;
constexpr float X_MIN = -51.2f, Y_MIN = -51.2f;
constexpr float RES_X = 102.4f / 128.0f;
constexpr float RES_Y = 102.4f / 128.0f;

// ---- ws layout (4-byte words), ~31.4 MB total ----
constexpr size_t WS_IMG_T = 0;                                      // float[B*HW*C] 1966080
constexpr size_t WS_HIST2 = WS_IMG_T + (size_t)B_DIM * HW * C_DIM;  // int[NSHARD*32768]
constexpr size_t WS_OUT_T = WS_HIST2 + (size_t)NSHARD * NCELL_TOT;  // float[NCELL_TOT*C] (adjacent -> fused memset)
constexpr size_t WS_HIST  = WS_OUT_T + (size_t)NCELL_TOT * C_DIM;   // int[32768]
constexpr size_t WS_OFFS  = WS_HIST + NCELL_TOT;                    // int[32769] (+3 pad)
constexpr size_t WS_EKEY  = WS_OFFS + NCELL_TOT + 4;                // int[MAX_ENTRIES]
constexpr size_t WS_EW16  = WS_EKEY + MAX_ENTRIES;                  // ushort[MAX_ENTRIES]
constexpr size_t WS_NEED_CM = (WS_EW16 + MAX_ENTRIES / 2) * 4;      // bytes, ~31.4 MB

__device__ inline int point_shard(int tid) {
    return ((tid >> 2) + (tid >> 8)) & (NSHARD - 1);   // deterministic in tid
}

__device__ inline void make_ray(const float* __restrict__ K, int b, float gx, float gy,
                                float& rx, float& ry, float& rz) {
    const float* Kb = K + b * 9;
    const float a00 = Kb[0], a01 = Kb[1], a02 = Kb[2];
    const float a10 = Kb[3], a11 = Kb[4], a12 = Kb[5];
    const float a20 = Kb[6], a21 = Kb[7], a22 = Kb[8];
    const float det = a00 * (a11 * a22 - a12 * a21)
                    - a01 * (a10 * a22 - a12 * a20)
                    + a02 * (a10 * a21 - a11 * a20);
    const float inv = 1.0f / det;
    const float i00 =  (a11 * a22 - a12 * a21) * inv;
    const float i01 = -(a01 * a22 - a02 * a21) * inv;
    const float i02 =  (a01 * a12 - a02 * a11) * inv;
    const float i10 = -(a10 * a22 - a12 * a20) * inv;
    const float i11 =  (a00 * a22 - a02 * a20) * inv;
    const float i12 = -(a00 * a12 - a02 * a10) * inv;
    const float i20 =  (a10 * a21 - a11 * a20) * inv;
    const float i21 = -(a00 * a21 - a01 * a20) * inv;
    const float i22 =  (a00 * a11 - a01 * a10) * inv;
    rx = i00 * gx + i01 * gy + i02;
    ry = i10 * gx + i11 * gy + i12;
    rz = i20 * gx + i21 * gy + i22;
}

// Returns global cell id (b*NCELL + cell) or -1. tid = ((b*D + d)*HW + pix).
__device__ inline int point_gcell(int tid, const float* __restrict__ dv,
                                  const float* __restrict__ K,
                                  const float* __restrict__ T) {
    const int pix = tid % HW;
    const int bd  = tid / HW;
    const int d   = bd % D_DIM;
    const int b   = bd / D_DIM;
    const int h = pix / IMG_W, w = pix % IMG_W;
    float rx, ry, rz;
    make_ray(K, b, (float)w, (float)h, rx, ry, rz);
    const float* Tb = T + b * 16;
    const float dep = dv[d];                       // wave-uniform
    const float px = dep * rx, py = dep * ry, pz = dep * rz;
    const float x = Tb[0] * px + Tb[1] * py + Tb[2]  * pz + Tb[3];
    const float y = Tb[4] * px + Tb[5] * py + Tb[6]  * pz + Tb[7];
    const float z = Tb[8] * px + Tb[9] * py + Tb[10] * pz + Tb[11];
    const int bx = (int)((x - X_MIN) / RES_X);     // truncate-toward-zero == astype(int32)
    const int by = (int)((y - Y_MIN) / RES_Y);
    const bool valid = (bx >= 0) && (bx < BEV_W) && (by >= 0) && (by < BEV_H) && (z > 0.0f);
    return valid ? (b * NCELL + by * BEV_W + bx) : -1;
}

// Wave-run helpers: lanes are consecutive pixels -> equal-cell runs.
__device__ inline bool wave_runs(int gcell, int lane, int& run_len, int& leader_idx) {
    const int left = __shfl_up(gcell, 1);          // width 64
    const bool is_leader = (lane == 0) || (left != gcell);
    const unsigned long long lmask = __ballot(is_leader);
    const unsigned long long rest = (lane == 63) ? 0ULL : (lmask >> (lane + 1));
    const int f = __ffsll((unsigned long long)rest);   // 1+idx or 0
    run_len = f ? f : (64 - lane);
    const unsigned long long below =
        lmask & ((lane == 63) ? ~0ULL : ((1ULL << (lane + 1)) - 1ULL));
    leader_idx = 63 - __clzll((long long)below);
    return is_leader;
}

// ---- K1: tiled transpose img[b,c,pix] -> img_t[b,pix,c] ----
__global__ __launch_bounds__(256) void k_transpose(const float* __restrict__ img,
                                                   float* __restrict__ img_t) {
    __shared__ float tile[32][33];
    const int b = blockIdx.z;
    const int tx = threadIdx.x, ty = threadIdx.y;      // block (32, 8)
    const int pix0 = blockIdx.x * 32, c0 = blockIdx.y * 32;
    #pragma unroll
    for (int j = 0; j < 32; j += 8)
        tile[ty + j][tx] = img[((size_t)(b * C_DIM + c0 + ty + j)) * HW + pix0 + tx];
    __syncthreads();
    #pragma unroll
    for (int j = 0; j < 32; j += 8)
        img_t[((size_t)(b * HW + pix0 + ty + j)) * C_DIM + c0 + tx] = tile[tx][ty + j];
}

// ---- K2: sharded count, one atomic per equal-cell run ----
__global__ __launch_bounds__(256) void k_count(const float* __restrict__ dv,
                                               const float* __restrict__ K,
                                               const float* __restrict__ T,
                                               int* __restrict__ hist2) {
    const int tid = blockIdx.x * 256 + threadIdx.x;   // < NPTS (exact grid)
    const int gcell = point_gcell(tid, dv, K, T);
    const int lane = threadIdx.x & 63;
    int run_len, leader_idx;
    const bool lead = wave_runs(gcell, lane, run_len, leader_idx);
    if (lead && gcell >= 0)
        atomicAdd(&hist2[(size_t)point_shard(tid) * NCELL_TOT + gcell], run_len);
}

// ---- K2b: reduce shards -> per-cell totals ----
__global__ __launch_bounds__(256) void k_reduce(const int* __restrict__ hist2,
                                                int* __restrict__ hist) {
    const int cell = blockIdx.x * 256 + threadIdx.x;  // 128 blocks exact
    int s = 0;
    #pragma unroll
    for (int sh = 0; sh < NSHARD; ++sh)
        s += hist2[(size_t)sh * NCELL_TOT + cell];
    hist[cell] = s;
}

// ---- K3: exclusive prefix scan over hist[32768] -> offs[32769] ----
__global__ __launch_bounds__(1024) void k_scan(const int* __restrict__ hist,
                                               int* __restrict__ offs) {
    __shared__ int lds[1024];
    const int t = threadIdx.x;
    int h[32];
    int s = 0;
    const int base = t * 32;
    #pragma unroll
    for (int k = 0; k < 32; ++k) { h[k] = hist[base + k]; s += h[k]; }
    lds[t] = s;
    __syncthreads();
    for (int off = 1; off < 1024; off <<= 1) {
        int v = (t >= off) ? lds[t - off] : 0;
        __syncthreads();
        lds[t] += v;
        __syncthreads();
    }
    int run = lds[t] - s;   // exclusive base for this thread's chunk
    #pragma unroll
    for (int k = 0; k < 32; ++k) {
        offs[base + k] = run;
        run += h[k];
    }
    if (t == 1023) offs[NCELL_TOT] = lds[1023];
}

// ---- K3b: per-cell shard prefix; hist2 becomes cursor bases in place ----
__global__ __launch_bounds__(256) void k_shardbase(int* __restrict__ hist2,
                                                   const int* __restrict__ offs) {
    const int cell = blockIdx.x * 256 + threadIdx.x;  // 128 blocks exact
    int run = offs[cell];
    #pragma unroll
    for (int sh = 0; sh < NSHARD; ++sh) {
        const size_t idx = (size_t)sh * NCELL_TOT + cell;
        const int cnt = hist2[idx];
        hist2[idx] = run;
        run += cnt;
    }
}

// ---- K4: fill entries; leader reserves a span per run, lanes write base+rank ----
__global__ __launch_bounds__(256) void k_fill(const float* __restrict__ dp,
                                              const float* __restrict__ dv,
                                              const float* __restrict__ K,
                                              const float* __restrict__ T,
                                              int* __restrict__ cursor2,   // = hist2 (bases)
                                              int* __restrict__ ekey,
                                              unsigned short* __restrict__ ew16) {
    const int tid = blockIdx.x * 256 + threadIdx.x;   // < NPTS (exact grid)
    const int gcell = point_gcell(tid, dv, K, T);
    const int lane = threadIdx.x & 63;
    int run_len, leader_idx;
    const bool lead = wave_runs(gcell, lane, run_len, leader_idx);
    int base = 0;
    if (lead && gcell >= 0)
        base = atomicAdd(&cursor2[(size_t)point_shard(tid) * NCELL_TOT + gcell], run_len);
    base = __shfl(base, leader_idx);                  // broadcast my run's base
    if (gcell < 0) return;
    const int slot = base + (lane - leader_idx);      // contiguous, coalesced writes
    const float p = dp[tid];                          // tid == ((b*D+d)*HW+pix): coalesced
    ekey[slot] = (gcell << 13) | (tid % HW);
    ew16[slot] = (unsigned short)__float2uint_rn(p * 65535.0f);
}

// ---- K5: chunked segmented reduction. One wave/block; thread = 2 channels
// (float2: one VMEM instr per entry fetches the whole 512B row).
// CELL_MAJOR: flush -> acc[gcell*C + c] (contiguous lines). else -> out layout.
template <bool CELL_MAJOR>
__global__ __launch_bounds__(64) void k_chunk_gather(
    const float* __restrict__ img_t,
    const int* __restrict__ offs,     // offs[NCELL_TOT] = total entry count
    const int* __restrict__ ekey,
    const unsigned short* __restrict__ ew16,
    float* __restrict__ acc_out)
{
    const int total = offs[NCELL_TOT];
    const int base = blockIdx.x * CHUNK;
    if (base >= total) return;

    __shared__ int   s_key[CHUNK];
    __shared__ float s_w[CHUNK];
    {
        const int i = threadIdx.x;                    // 64 threads, CHUNK=64
        const int idx = min(base + i, total - 1);
        s_key[i] = ekey[idx];                         // pad = dup of last key
        s_w[i]   = (base + i < total) ? (float)ew16[base + i] * (1.0f / 65535.0f)
                                      : 0.0f;         // pad weight 0 -> no-op
    }
    __syncthreads();

    const int c2 = threadIdx.x * 2;                   // channels c2, c2+1
    int prev = s_key[0] >> 13;
    float2 acc = make_float2(0.0f, 0.0f);
    #pragma unroll 8
    for (int k = 0; k < CHUNK; ++k) {                 // static trip count -> pipelined
        const int key = s_key[k];                     // LDS broadcast (wave-uniform)
        const float wgt = s_w[k];
        const int gcell = key >> 13;
        const int pix = key & 8191;
        const int b = gcell >> 14;
        const float2 v = *reinterpret_cast<const float2*>(
            &img_t[((size_t)(b * HW + pix)) * C_DIM + c2]);   // 8B/lane, coalesced
        if (gcell != prev) {                          // wave-uniform branch
            if (CELL_MAJOR) {
                float* o = &acc_out[(size_t)prev * C_DIM + c2];
                atomicAdd(o, acc.x);
                atomicAdd(o + 1, acc.y);
            } else {
                const int pb = prev >> 14, pc = prev & (NCELL - 1);
                float* o = &acc_out[((size_t)(pb * C_DIM + c2)) * NCELL + pc];
                atomicAdd(o, acc.x);
                atomicAdd(o + NCELL, acc.y);
            }
            acc = make_float2(0.0f, 0.0f);
            prev = gcell;
        }
        acc.x = fmaf(v.x, wgt, acc.x);
        acc.y = fmaf(v.y, wgt, acc.y);
    }
    if (CELL_MAJOR) {
        float* o = &acc_out[(size_t)prev * C_DIM + c2];
        atomicAdd(o, acc.x);
        atomicAdd(o + 1, acc.y);
    } else {
        const int pb = prev >> 14, pc = prev & (NCELL - 1);
        float* o = &acc_out[((size_t)(pb * C_DIM + c2)) * NCELL + pc];
        atomicAdd(o, acc.x);
        atomicAdd(o + NCELL, acc.y);
    }
}

// ---- K6: untranspose out_t[b][cell][c] -> out[b][c][cell] ----
__global__ __launch_bounds__(256) void k_untranspose(const float* __restrict__ out_t,
                                                     float* __restrict__ out) {
    __shared__ float tile[32][33];
    const int b = blockIdx.z;
    const int tx = threadIdx.x, ty = threadIdx.y;      // block (32, 8)
    const int cell0 = blockIdx.x * 32, c0 = blockIdx.y * 32;
    const float* src = out_t + (size_t)b * NCELL * C_DIM;
    #pragma unroll
    for (int j = 0; j < 32; j += 8)                    // read: c contiguous
        tile[ty + j][tx] = src[((size_t)(cell0 + ty + j)) * C_DIM + c0 + tx];
    __syncthreads();
    #pragma unroll
    for (int j = 0; j < 32; j += 8)                    // write: cell contiguous
        out[((size_t)(b * C_DIM + c0 + ty + j)) * NCELL + cell0 + tx] = tile[tx][ty + j];
}

extern "C" void kernel_launch(void* const* d_in, const int* in_sizes, int n_in,
                              void* d_out, int out_size, void* d_ws, size_t ws_size,
                              hipStream_t stream) {
    const float* img = (const float*)d_in[0];
    const float* dp  = (const float*)d_in[1];
    const float* dv  = (const float*)d_in[2];
    const float* K   = (const float*)d_in[3];
    const float* T   = (const float*)d_in[4];
    float* out = (float*)d_out;

    float* ws_f   = (float*)d_ws;
    float* img_t  = ws_f + WS_IMG_T;
    int*   hist2  = (int*)d_ws + WS_HIST2;
    float* out_t  = ws_f + WS_OUT_T;
    int*   hist   = (int*)d_ws + WS_HIST;
    int*   offs   = (int*)d_ws + WS_OFFS;
    int*   ekey   = (int*)d_ws + WS_EKEY;
    unsigned short* ew16 = (unsigned short*)((int*)d_ws + WS_EW16);

    const bool cell_major = (ws_size >= WS_NEED_CM);

    if (cell_major) {
        // hist2 and out_t are adjacent -> one fused memset (2 MB + 16 MB)
        hipMemsetAsync(hist2, 0,
                       ((size_t)NSHARD * NCELL_TOT + (size_t)NCELL_TOT * C_DIM) * sizeof(int),
                       stream);
    } else {
        hipMemsetAsync(hist2, 0, (size_t)NSHARD * NCELL_TOT * sizeof(int), stream);
        hipMemsetAsync(out, 0, (size_t)out_size * sizeof(float), stream);
    }

    k_transpose<<<dim3(HW / 32, C_DIM / 32, B_DIM), dim3(32, 8), 0, stream>>>(img, img_t);
    k_count<<<NPTS / 256, 256, 0, stream>>>(dv, K, T, hist2);
    k_reduce<<<NCELL_TOT / 256, 256, 0, stream>>>(hist2, hist);
    k_scan<<<1, 1024, 0, stream>>>(hist, offs);
    k_shardbase<<<NCELL_TOT / 256, 256, 0, stream>>>(hist2, offs);
    k_fill<<<NPTS / 256, 256, 0, stream>>>(dp, dv, K, T, hist2, ekey, ew16);
    if (cell_major) {
        k_chunk_gather<true><<<MAX_ENTRIES / CHUNK, 64, 0, stream>>>(
            img_t, offs, ekey, ew16, out_t);
        k_untranspose<<<dim3(NCELL / 32, C_DIM / 32, B_DIM), dim3(32, 8), 0, stream>>>(
            out_t, out);
    } else {
        k_chunk_gather<false><<<MAX_ENTRIES / CHUNK, 64, 0, stream>>>(
            img_t, offs, ekey, ew16, out);
    }
}